// Round 1
// baseline (185.370 us; speedup 1.0000x reference)
//
#include <hip/hip_runtime.h>
#include <hip/hip_bf16.h>

// Problem constants (from reference setup_inputs)
// B=2, S=2048, D=512, K=64, H=8 (heads irrelevant: weighted sum is head-uniform)

#define BM 64
#define BN 64
#define BK 16
#define PAD 4   // keeps LDS rows 16B-aligned -> ds_read_b128; 2-way bank alias only (free)

// C[m,n] = sum_k A[m,k] * B[n,k]  (+ bias[n] + residual[m,n] if non-null)
// A: M x K row-major, B: N x K row-major (i.e. C = A * B^T)
__global__ __launch_bounds__(256) void gemm_nt(
    const float* __restrict__ A, const float* __restrict__ Bmat,
    float* __restrict__ C, const float* __restrict__ residual,
    const float* __restrict__ bias, int M, int N, int K)
{
    __shared__ float As[BK][BM + PAD];
    __shared__ float Bs[BK][BN + PAD];

    const int tid = threadIdx.x;
    const int tx = tid % 16;      // col group
    const int ty = tid / 16;      // row group
    const int m0 = blockIdx.y * BM;
    const int n0 = blockIdx.x * BN;

    // loader mapping: 256 threads x float4 = 1024 floats = one 64x16 tile
    const int lrow = tid / 4;           // 0..63
    const int lcol = (tid % 4) * 4;     // 0,4,8,12

    float acc[4][4];
    #pragma unroll
    for (int i = 0; i < 4; ++i)
        #pragma unroll
        for (int j = 0; j < 4; ++j) acc[i][j] = 0.f;

    for (int k0 = 0; k0 < K; k0 += BK) {
        const float4 a4 = *(const float4*)(A    + (size_t)(m0 + lrow) * K + k0 + lcol);
        const float4 b4 = *(const float4*)(Bmat + (size_t)(n0 + lrow) * K + k0 + lcol);
        As[lcol + 0][lrow] = a4.x; As[lcol + 1][lrow] = a4.y;
        As[lcol + 2][lrow] = a4.z; As[lcol + 3][lrow] = a4.w;
        Bs[lcol + 0][lrow] = b4.x; Bs[lcol + 1][lrow] = b4.y;
        Bs[lcol + 2][lrow] = b4.z; Bs[lcol + 3][lrow] = b4.w;
        __syncthreads();

        #pragma unroll
        for (int kk = 0; kk < BK; ++kk) {
            float a[4], b[4];
            #pragma unroll
            for (int i = 0; i < 4; ++i) a[i] = As[kk][ty * 4 + i];
            #pragma unroll
            for (int j = 0; j < 4; ++j) b[j] = Bs[kk][tx * 4 + j];
            #pragma unroll
            for (int i = 0; i < 4; ++i)
                #pragma unroll
                for (int j = 0; j < 4; ++j)
                    acc[i][j] = fmaf(a[i], b[j], acc[i][j]);
        }
        __syncthreads();
    }

    #pragma unroll
    for (int i = 0; i < 4; ++i) {
        const int m = m0 + ty * 4 + i;
        #pragma unroll
        for (int j = 0; j < 4; ++j) {
            const int n = n0 + tx * 4 + j;
            float v = acc[i][j];
            if (bias)     v += bias[n];
            if (residual) v += residual[(size_t)m * N + n];
            C[(size_t)m * N + n] = v;
        }
    }
}

// w[s,k] = softmax_k( -distances[s, routes[s,k]] ), one wave per s
__global__ __launch_bounds__(64) void softmax_w(
    const int* __restrict__ routes, const float* __restrict__ distances,
    float* __restrict__ w, int S, int K)
{
    const int s = blockIdx.x;
    const int k = threadIdx.x;
    const int r = routes[s * K + k];
    const float v = -distances[(size_t)s * S + r];

    float m = v;
    #pragma unroll
    for (int off = 32; off >= 1; off >>= 1) m = fmaxf(m, __shfl_xor(m, off, 64));
    const float e = __expf(v - m);
    float sum = e;
    #pragma unroll
    for (int off = 32; off >= 1; off >>= 1) sum += __shfl_xor(sum, off, 64);
    w[s * K + k] = e / sum;
}

// fused[b,s,:] = sum_k w[s,k] * h[b, routes[s,k], :]
// grid (S, B), 256 threads; each thread covers elements tid and tid+256 of D=512
__global__ __launch_bounds__(256) void fuse_gather(
    const float* __restrict__ h, const int* __restrict__ routes,
    const float* __restrict__ w, float* __restrict__ fused,
    int S, int D, int K)
{
    const int s = blockIdx.x;
    const int b = blockIdx.y;
    const int tid = threadIdx.x;

    __shared__ float wsm[64];
    __shared__ int   rsm[64];
    if (tid < 64) {
        wsm[tid] = w[s * K + tid];
        rsm[tid] = routes[s * K + tid];
    }
    __syncthreads();

    const float* hb = h + (size_t)b * S * D;
    float acc0 = 0.f, acc1 = 0.f;
    #pragma unroll 8
    for (int k = 0; k < 64; ++k) {
        const float* row = hb + (size_t)rsm[k] * D;
        const float wk = wsm[k];
        acc0 = fmaf(wk, row[tid],       acc0);
        acc1 = fmaf(wk, row[tid + 256], acc1);
    }
    const size_t o = ((size_t)b * S + s) * (size_t)D;
    fused[o + tid]       = acc0;
    fused[o + tid + 256] = acc1;
}

extern "C" void kernel_launch(void* const* d_in, const int* in_sizes, int n_in,
                              void* d_out, int out_size, void* d_ws, size_t ws_size,
                              hipStream_t stream) {
    const float* x         = (const float*)d_in[0];
    const int*   routes    = (const int*)  d_in[1];
    const float* distances = (const float*)d_in[2];
    const float* W_in      = (const float*)d_in[3];
    const float* W_out     = (const float*)d_in[4];
    const float* b_out     = (const float*)d_in[5];
    float* out = (float*)d_out;

    const int B = 2, S = 2048, D = 512, K = 64;
    const int M = B * S;

    // workspace layout: h (8 MB) | fused (8 MB) | w (512 KB)
    float* h     = (float*)d_ws;
    float* fused = h + (size_t)M * D;
    float* w     = fused + (size_t)M * D;

    const dim3 gblock(256);
    const dim3 ggrid(D / BN, M / BM);   // 8 x 64

    // 1. h = x @ W_in^T
    gemm_nt<<<ggrid, gblock, 0, stream>>>(x, W_in, h, nullptr, nullptr, M, D, D);
    // 2. softmax weights
    softmax_w<<<S, 64, 0, stream>>>(routes, distances, w, S, K);
    // 3. gather + weighted sum
    fuse_gather<<<dim3(S, B), 256, 0, stream>>>(h, routes, w, fused, S, D, K);
    // 4. out = fused @ W_out^T + b_out + x
    gemm_nt<<<ggrid, gblock, 0, stream>>>(fused, W_out, out, x, b_out, M, D, D);
}

// Round 2
// 121.921 us; speedup vs baseline: 1.5204x; 1.5204x over previous
//
#include <hip/hip_runtime.h>
#include <hip/hip_bf16.h>

// B=2, S=2048, D=512, K_routes=64, H=8 (heads irrelevant: k-weighted sum is head-uniform)
#define S_DIM 2048
#define D_DIM 512
#define B_DIM 2
#define K_RT  64

typedef __attribute__((ext_vector_type(8))) short short8;   // 8 bf16 = 4 VGPRs (MFMA A/B frag)
typedef __attribute__((ext_vector_type(4))) float f32x4;    // MFMA C/D frag

static __device__ __forceinline__ float bf16lo_to_f(unsigned u) {
    union { unsigned u; float f; } c; c.u = u << 16; return c.f;
}
static __device__ __forceinline__ float bf16hi_to_f(unsigned u) {
    union { unsigned u; float f; } c; c.u = u & 0xffff0000u; return c.f;
}
static __device__ __forceinline__ unsigned short f_to_bf16(float f) {
    union { float f; unsigned u; } c; c.f = f;
    unsigned u = c.u;
    u += 0x7fffu + ((u >> 16) & 1u);   // round-to-nearest-even (inputs are finite/normal)
    return (unsigned short)(u >> 16);
}

// ---------------------------------------------------------------------------
// cast x (2M), W_in (256K), W_out (256K) fp32 -> bf16. 4 elems/thread, exact grid.
__global__ __launch_bounds__(256) void cast_all(
    const float* __restrict__ x, const float* __restrict__ Wi, const float* __restrict__ Wo,
    unsigned short* __restrict__ xb, unsigned short* __restrict__ wib, unsigned short* __restrict__ wob)
{
    const int g = blockIdx.x * 256 + threadIdx.x;       // one per float4
    const int NX = B_DIM * S_DIM * D_DIM / 4;           // 524288
    const int NW = D_DIM * D_DIM / 4;                   // 65536
    const float* src; unsigned short* dst; int off;
    if (g < NX)           { src = x;  dst = xb;  off = g; }
    else if (g < NX + NW) { src = Wi; dst = wib; off = g - NX; }
    else                  { src = Wo; dst = wob; off = g - NX - NW; }
    const float4 v = ((const float4*)src)[off];
    ushort4 o;
    o.x = f_to_bf16(v.x); o.y = f_to_bf16(v.y);
    o.z = f_to_bf16(v.z); o.w = f_to_bf16(v.w);
    ((ushort4*)dst)[off] = o;
}

// ---------------------------------------------------------------------------
// C = A * B^T, bf16 inputs (both K-contiguous), fp32 accumulate via MFMA.
// 64x64 block tile, 4 waves each 32x32 (2x2 frags of 16x16x32), BK=32.
// Cb!=null -> write bf16; Cf!=null -> write fp32 + bias[n] + residual[m,n].
#define GBM 64
#define GBN 64
#define GBK 32
#define LROW 40   // padded LDS row (bf16 elems): 80 B stride -> 20-bank rotation, 2-way max (free)

__global__ __launch_bounds__(256) void gemm_bt_bf16(
    const unsigned short* __restrict__ A,   // M x K bf16
    const unsigned short* __restrict__ B,   // N x K bf16
    unsigned short* __restrict__ Cb,
    float* __restrict__ Cf,
    const float* __restrict__ bias, const float* __restrict__ residual,
    int M, int N, int K)
{
    __shared__ unsigned short As[GBM * LROW];
    __shared__ unsigned short Bs[GBN * LROW];

    const int tid  = threadIdx.x;
    const int lane = tid & 63;
    const int wv   = tid >> 6;          // wave 0..3
    const int wm   = (wv & 1) * 32;
    const int wn   = (wv >> 1) * 32;
    const int m0   = blockIdx.y * GBM;
    const int n0   = blockIdx.x * GBN;

    // staging map: 256 threads x 16 B = one 64x32 bf16 tile
    const int lr = tid >> 2;            // row 0..63
    const int lc = (tid & 3) * 8;       // k-elem offset 0,8,16,24

    const int mi = lane & 15;           // frag row/col within 16
    const int kg = lane >> 4;           // k-group 0..3 (k = kg*8 + j)

    f32x4 acc[2][2] = {};

    for (int k0 = 0; k0 < K; k0 += GBK) {
        const uint4 a4 = *(const uint4*)(A + (size_t)(m0 + lr) * K + k0 + lc);
        const uint4 b4 = *(const uint4*)(B + (size_t)(n0 + lr) * K + k0 + lc);
        *(uint4*)(As + lr * LROW + lc) = a4;
        *(uint4*)(Bs + lr * LROW + lc) = b4;
        __syncthreads();

        short8 af0 = *(const short8*)(As + (wm +      mi) * LROW + kg * 8);
        short8 af1 = *(const short8*)(As + (wm + 16 + mi) * LROW + kg * 8);
        short8 bf0 = *(const short8*)(Bs + (wn +      mi) * LROW + kg * 8);
        short8 bf1 = *(const short8*)(Bs + (wn + 16 + mi) * LROW + kg * 8);

        acc[0][0] = __builtin_amdgcn_mfma_f32_16x16x32_bf16(af0, bf0, acc[0][0], 0, 0, 0);
        acc[0][1] = __builtin_amdgcn_mfma_f32_16x16x32_bf16(af0, bf1, acc[0][1], 0, 0, 0);
        acc[1][0] = __builtin_amdgcn_mfma_f32_16x16x32_bf16(af1, bf0, acc[1][0], 0, 0, 0);
        acc[1][1] = __builtin_amdgcn_mfma_f32_16x16x32_bf16(af1, bf1, acc[1][1], 0, 0, 0);
        __syncthreads();
    }

    // C/D layout: col = lane&15, row = (lane>>4)*4 + reg   [verified m89/m91]
    const int rb  = (lane >> 4) * 4;
    const int col = lane & 15;
    #pragma unroll
    for (int i = 0; i < 2; ++i) {
        #pragma unroll
        for (int j = 0; j < 2; ++j) {
            #pragma unroll
            for (int r = 0; r < 4; ++r) {
                const int m = m0 + wm + i * 16 + rb + r;
                const int n = n0 + wn + j * 16 + col;
                const float v = acc[i][j][r];
                if (Cf) {
                    Cf[(size_t)m * N + n] = v + bias[n] + residual[(size_t)m * N + n];
                } else {
                    Cb[(size_t)m * N + n] = f_to_bf16(v);
                }
            }
        }
    }
}

// ---------------------------------------------------------------------------
// fused[b,s,:] = sum_k softmax_k(-dist[s,routes[s,k]]) * h[b,routes[s,k],:]
// One wave per (b,s): lane k owns route_k/w_k (in-register softmax), then the
// k-loop broadcasts via __shfl and all 64 lanes read one 1 KB bf16 row (uint4/lane).
__global__ __launch_bounds__(256) void fuse_gather(
    const unsigned short* __restrict__ h, const int* __restrict__ routes,
    const float* __restrict__ distances, unsigned short* __restrict__ fused)
{
    const int tid  = threadIdx.x;
    const int lane = tid & 63;
    const int wv   = tid >> 6;
    const int s    = blockIdx.x * 4 + wv;
    const int b    = blockIdx.y;

    const int rt = routes[s * K_RT + lane];
    const float v = -distances[(size_t)s * S_DIM + rt];
    float mx = v;
    #pragma unroll
    for (int off = 32; off >= 1; off >>= 1) mx = fmaxf(mx, __shfl_xor(mx, off, 64));
    const float e = __expf(v - mx);
    float sum = e;
    #pragma unroll
    for (int off = 32; off >= 1; off >>= 1) sum += __shfl_xor(sum, off, 64);
    const float wl = e / sum;

    const unsigned short* hb = h + (size_t)b * S_DIM * D_DIM;
    float acc[8] = {};
    #pragma unroll 4
    for (int k = 0; k < 64; ++k) {
        const int   rk = __shfl(rt, k, 64);
        const float wk = __shfl(wl, k, 64);
        const uint4 p = *(const uint4*)(hb + (size_t)rk * D_DIM + lane * 8);
        acc[0] = fmaf(wk, bf16lo_to_f(p.x), acc[0]);
        acc[1] = fmaf(wk, bf16hi_to_f(p.x), acc[1]);
        acc[2] = fmaf(wk, bf16lo_to_f(p.y), acc[2]);
        acc[3] = fmaf(wk, bf16hi_to_f(p.y), acc[3]);
        acc[4] = fmaf(wk, bf16lo_to_f(p.z), acc[4]);
        acc[5] = fmaf(wk, bf16hi_to_f(p.z), acc[5]);
        acc[6] = fmaf(wk, bf16lo_to_f(p.w), acc[6]);
        acc[7] = fmaf(wk, bf16hi_to_f(p.w), acc[7]);
    }
    uint4 o;
    o.x = (unsigned)f_to_bf16(acc[0]) | ((unsigned)f_to_bf16(acc[1]) << 16);
    o.y = (unsigned)f_to_bf16(acc[2]) | ((unsigned)f_to_bf16(acc[3]) << 16);
    o.z = (unsigned)f_to_bf16(acc[4]) | ((unsigned)f_to_bf16(acc[5]) << 16);
    o.w = (unsigned)f_to_bf16(acc[6]) | ((unsigned)f_to_bf16(acc[7]) << 16);
    *(uint4*)(fused + ((size_t)b * S_DIM + s) * D_DIM + lane * 8) = o;
}

// ---------------------------------------------------------------------------
extern "C" void kernel_launch(void* const* d_in, const int* in_sizes, int n_in,
                              void* d_out, int out_size, void* d_ws, size_t ws_size,
                              hipStream_t stream) {
    const float* x         = (const float*)d_in[0];
    const int*   routes    = (const int*)  d_in[1];
    const float* distances = (const float*)d_in[2];
    const float* W_in      = (const float*)d_in[3];
    const float* W_out     = (const float*)d_in[4];
    const float* b_out     = (const float*)d_in[5];
    float* out = (float*)d_out;

    const int M = B_DIM * S_DIM;   // 4096

    // ws layout (bf16 elems): xb 2M | wib 256K | wob 256K | h 2M | fused 2M  = 13 MB
    unsigned short* xb  = (unsigned short*)d_ws;
    unsigned short* wib = xb  + (size_t)M * D_DIM;
    unsigned short* wob = wib + (size_t)D_DIM * D_DIM;
    unsigned short* hb  = wob + (size_t)D_DIM * D_DIM;
    unsigned short* fb  = hb  + (size_t)M * D_DIM;

    // 1. casts (exact grid: (2M + 2*256K)/4 threads = 655360 = 2560*256)
    cast_all<<<2560, 256, 0, stream>>>(x, W_in, W_out, xb, wib, wob);
    // 2. h = x @ W_in^T  (bf16 out)
    gemm_bt_bf16<<<dim3(D_DIM / GBN, M / GBM), 256, 0, stream>>>(
        xb, wib, hb, nullptr, nullptr, nullptr, M, D_DIM, D_DIM);
    // 3. softmax + gather + weighted sum (bf16 out)
    fuse_gather<<<dim3(S_DIM / 4, B_DIM), 256, 0, stream>>>(hb, routes, distances, fb);
    // 4. out = fused @ W_out^T + b_out + x  (fp32 out)
    gemm_bt_bf16<<<dim3(D_DIM / GBN, M / GBM), 256, 0, stream>>>(
        fb, wob, nullptr, out, b_out, x, M, D_DIM, D_DIM);
}